// Round 5
// baseline (3730.095 us; speedup 1.0000x reference)
//
#include <hip/hip_runtime.h>

// ---------------- problem constants ----------------
#define NB    256
#define TLEN  1632
#define HIDC  64
#define CBD   512
#define NTOK  1024
#define T2L   816          // after enc conv1
#define T4L   408          // after enc conv2 (token count per batch)
#define MTOK  (NB*T4L)     // 104448 tokens
#define M2TOK (NB*T2L)     // 208896
#define MOUT  (NB*TLEN)    // 417792

// d_out flat offsets (floats)
#define DO_OUT    ((size_t)0)
#define DO_RECON  ((size_t)417792)
#define DO_COMMIT ((size_t)417793)
#define DO_IDX    ((size_t)417795)
#define DO_QUANT  ((size_t)626691)

// ---------------- workspace layout (float indices) ----------------
static constexpr size_t N_XR   = (size_t)MTOK * CBD;        // 53,477,376 (xr/residual; later d2buf)
static constexpr size_t OFF_XR = 0;
static constexpr size_t OFF_H1 = OFF_XR + N_XR;             // h1, later d1  [256*816*64]
static constexpr size_t N_H1   = (size_t)NB * T2L * HIDC;
static constexpr size_t OFF_H2 = OFF_H1 + N_H1;             // h2 [256*408*64]
static constexpr size_t N_H2   = (size_t)NB * T4L * HIDC;
static constexpr size_t OFF_BE2 = OFF_H2 + N_H2;            // 64*128
static constexpr size_t OFF_BD1 = OFF_BE2 + 8192;           // 128*512
static constexpr size_t OFF_BD2 = OFF_BD1 + 65536;          // 128*64
static constexpr size_t OFF_BX1 = OFF_BD2 + 8192;           // 128 expanded bias d1
static constexpr size_t OFF_BX2 = OFF_BX1 + 128;            // 128 expanded bias d2
static constexpr size_t OFF_C2  = OFF_BX2 + 128;            // 2048 codebook norms
static constexpr size_t OFF_R2  = OFF_C2 + 2048;            // 104448 token norms
static constexpr size_t OFF_SLOT= OFF_R2 + MTOK;            // 1536 loss slots (recon, c0, c1)
static constexpr size_t OFF_IDXI= OFF_SLOT + 1536;          // 104448*2 ints
static constexpr size_t OFF_KEYS= OFF_IDXI + (size_t)MTOK*2;// 2*104448 u64 (even float offset -> 8B aligned)

// ---------------- helpers ----------------
__device__ inline unsigned long long shfl_xor_u64_w16(unsigned long long v, int m) {
    unsigned lo = (unsigned)v, hi = (unsigned)(v >> 32);
    lo = __shfl_xor(lo, m, 16);
    hi = __shfl_xor(hi, m, 16);
    return (((unsigned long long)hi) << 32) | lo;
}

// ---------------- weight prep ----------------
__global__ void prep_kernel(const float* __restrict__ We2, const float* __restrict__ Wtd1,
                            const float* __restrict__ Wtd2, const float* __restrict__ bd1,
                            const float* __restrict__ bd2,
                            float* __restrict__ Be2, float* __restrict__ Bd1,
                            float* __restrict__ Bd2, float* __restrict__ bx1, float* __restrict__ bx2) {
    int i = blockIdx.x * blockDim.x + threadIdx.x;
    int stride = gridDim.x * blockDim.x;
    // Be2[c][k], k = tap*64 + ch  ->  We2[c][ch][tap]
    for (int x = i; x < 64 * 128; x += stride) {
        int c = x >> 7, k = x & 127;
        Be2[x] = We2[c * 128 + ((k & 63) << 1) + (k >> 6)];
    }
    // Bd1[n][k] = Wtd1[k*128 + n]   (n = co*2+tap, k = ci)
    for (int x = i; x < 128 * 512; x += stride) {
        int n = x >> 9, k = x & 511;
        Bd1[x] = Wtd1[k * 128 + n];
    }
    // Bd2[n][k] = Wtd2[k*128 + n]
    for (int x = i; x < 128 * 64; x += stride) {
        int n = x >> 6, k = x & 63;
        Bd2[x] = Wtd2[k * 128 + n];
    }
    for (int x = i; x < 128; x += stride) { bx1[x] = bd1[x >> 1]; bx2[x] = bd2[x >> 1]; }
}

// ---------------- row sum-of-squares (512-wide rows): one wave per row ----------------
__global__ void rownorm_kernel(const float* __restrict__ X, float* __restrict__ out, int rows) {
    int w = (blockIdx.x * blockDim.x + threadIdx.x) >> 6;
    int lane = threadIdx.x & 63;
    if (w >= rows) return;
    const float* r = X + (size_t)w * 512;
    float4 a = *(const float4*)(r + lane * 8);
    float4 b = *(const float4*)(r + lane * 8 + 4);
    float s = a.x*a.x + a.y*a.y + a.z*a.z + a.w*a.w + b.x*b.x + b.y*b.y + b.z*b.z + b.w*b.w;
    #pragma unroll
    for (int o = 32; o > 0; o >>= 1) s += __shfl_down(s, o, 64);
    if (lane == 0) out[w] = s;
}

// ---------------- encoder conv1 (Cin=1, k2s2) -> h1 token-major [b][t][c] ----------------
__global__ void enc1_kernel(const float* __restrict__ img, const float* __restrict__ W,
                            const float* __restrict__ bias, float* __restrict__ h1) {
    int idx = blockIdx.x * 256 + threadIdx.x;          // over 256*816*64
    int c = idx & 63;
    int t = (idx >> 6) % T2L;
    int b = idx / (64 * T2L);
    float v = W[c * 2] * img[(size_t)b * TLEN + 2 * t] +
              W[c * 2 + 1] * img[(size_t)b * TLEN + 2 * t + 1] + bias[c];
    h1[idx] = fmaxf(v, 0.f);
}

// ---------------- generic NT SGEMM: C[M,N] = A[M,K] . B[N,K]^T + bias ----------------
// tile 128(M) x 64(N), K-chunk 32, 256 threads, 8x4 microtile
// amode: 0 plain row-major A (ld=K); 1 e2 concat-token view of h1; 2 channel-major quantized
// cmode: 0 C[m*N+n]; 1 convT1 interleave (Tin=408); 2 convT2 interleave (Tin=816)
__global__ __launch_bounds__(256) void gemm_nt(const float* __restrict__ A, const float* __restrict__ Bw,
                        const float* __restrict__ bias, float* __restrict__ C,
                        int M, int N, int K, int amode, int cmode, int relu) {
    __shared__ float As[32][132];
    __shared__ float Bs[32][68];
    int m0 = blockIdx.x * 128;
    int n0 = blockIdx.y * 64;
    int tid = threadIdx.x;
    int tx = tid & 15;
    int ty = tid >> 4;
    float acc[8][4];
    #pragma unroll
    for (int i = 0; i < 8; ++i)
        #pragma unroll
        for (int j = 0; j < 4; ++j) acc[i][j] = 0.f;

    for (int k0 = 0; k0 < K; k0 += 32) {
        if (amode != 2) {
            #pragma unroll
            for (int i = 0; i < 4; ++i) {
                int idx = tid + i * 256;           // 0..1023
                int row = idx >> 3;
                int kq = idx & 7;
                int m = m0 + row;
                size_t base;
                if (amode == 0) base = (size_t)m * K;
                else            base = (size_t)(((m / T4L) * T2L + 2 * (m % T4L)) * 64);
                float4 v = *(const float4*)(A + base + k0 + kq * 4);
                int kk = kq * 4;
                As[kk + 0][row] = v.x; As[kk + 1][row] = v.y;
                As[kk + 2][row] = v.z; As[kk + 3][row] = v.w;
            }
        } else {
            // quantized channel-major: addr = ((m/408)*512 + k)*408 + (m%408)
            int ml = tid & 127;
            int kl = tid >> 7;                     // 0..1
            int m = m0 + ml;
            int b = m / T4L, t = m % T4L;
            size_t rowbase = ((size_t)b * 512) * T4L + t;
            for (int kk = kl; kk < 32; kk += 2)
                As[kk][ml] = A[rowbase + (size_t)(k0 + kk) * T4L];
        }
        #pragma unroll
        for (int i = 0; i < 2; ++i) {
            int idx = tid + i * 256;               // 0..511
            int row = idx >> 3;
            int kq = idx & 7;
            float4 v = *(const float4*)(Bw + (size_t)(n0 + row) * K + k0 + kq * 4);
            int kk = kq * 4;
            Bs[kk + 0][row] = v.x; Bs[kk + 1][row] = v.y;
            Bs[kk + 2][row] = v.z; Bs[kk + 3][row] = v.w;
        }
        __syncthreads();
        #pragma unroll
        for (int kk = 0; kk < 32; ++kk) {
            float a[8], bf[4];
            float4 a0 = *(const float4*)&As[kk][ty * 8];
            float4 a1 = *(const float4*)&As[kk][ty * 8 + 4];
            a[0]=a0.x; a[1]=a0.y; a[2]=a0.z; a[3]=a0.w;
            a[4]=a1.x; a[5]=a1.y; a[6]=a1.z; a[7]=a1.w;
            float4 b0 = *(const float4*)&Bs[kk][tx * 4];
            bf[0]=b0.x; bf[1]=b0.y; bf[2]=b0.z; bf[3]=b0.w;
            #pragma unroll
            for (int i = 0; i < 8; ++i)
                #pragma unroll
                for (int j = 0; j < 4; ++j) acc[i][j] += a[i] * bf[j];
        }
        __syncthreads();
    }
    // epilogue
    #pragma unroll
    for (int i = 0; i < 8; ++i) {
        int m = m0 + ty * 8 + i;
        if (cmode == 0) {
            float4 v;
            float b0 = bias[n0 + tx * 4 + 0], b1 = bias[n0 + tx * 4 + 1];
            float b2 = bias[n0 + tx * 4 + 2], b3 = bias[n0 + tx * 4 + 3];
            v.x = acc[i][0] + b0; v.y = acc[i][1] + b1;
            v.z = acc[i][2] + b2; v.w = acc[i][3] + b3;
            if (relu) { v.x=fmaxf(v.x,0.f); v.y=fmaxf(v.y,0.f); v.z=fmaxf(v.z,0.f); v.w=fmaxf(v.w,0.f); }
            *(float4*)(C + (size_t)m * N + n0 + tx * 4) = v;
        } else {
            int Tin = (cmode == 1) ? T4L : T2L;
            int Texp = 2 * Tin;
            int bb = m / Tin, t = m % Tin;
            #pragma unroll
            for (int j = 0; j < 4; ++j) {
                int n = n0 + tx * 4 + j;
                float v = acc[i][j] + bias[n];
                if (relu) v = fmaxf(v, 0.f);
                size_t off = (size_t)((bb * Texp + 2 * t + (n & 1)) * 64 + (n >> 1));
                C[off] = v;
            }
        }
    }
}

// ---------------- VQ distance GEMM + argmin epilogue ----------------
// 256x128 tile, 16x8 microtile, K-chunk 32, register-transposed staging.
// ALL accumulators/fragments are NAMED variables (no arrays) to force VGPR allocation.
#define DECL(I) float4 accA##I = {0.f,0.f,0.f,0.f}; float4 accB##I = {0.f,0.f,0.f,0.f};

#define RF(I, S) { accA##I.x += (S)*b0.x; accA##I.y += (S)*b0.y; accA##I.z += (S)*b0.z; accA##I.w += (S)*b0.w; \
                   accB##I.x += (S)*b1.x; accB##I.y += (S)*b1.y; accB##I.z += (S)*b1.z; accB##I.w += (S)*b1.w; }

#define XP(arr, krow, cbase, r0, r1, r2, r3) { \
    float4 t0; t0.x=r0.x; t0.y=r1.x; t0.z=r2.x; t0.w=r3.x; *(float4*)&arr[(krow)+0][cbase] = t0; \
    float4 t1; t1.x=r0.y; t1.y=r1.y; t1.z=r2.y; t1.w=r3.y; *(float4*)&arr[(krow)+1][cbase] = t1; \
    float4 t2; t2.x=r0.z; t2.y=r1.z; t2.z=r2.z; t2.w=r3.z; *(float4*)&arr[(krow)+2][cbase] = t2; \
    float4 t3; t3.x=r0.w; t3.y=r1.w; t3.z=r2.w; t3.w=r3.w; *(float4*)&arr[(krow)+3][cbase] = t3; }

#define KEYUPD(D, N) { float d2v = (rr - 2.0f*(D)) + c2[N]; unsigned u = __float_as_uint(d2v); \
    u = (u & 0x80000000u) ? ~u : (u | 0x80000000u); \
    unsigned long long key = (((unsigned long long)u) << 32) | (unsigned)(N); if (key < best) best = key; }

#define EPI(I) { int m = m0 + ((I) >> 2) * 64 + ty * 4 + ((I) & 3); float rr = r2[m]; \
    unsigned long long best = ~0ull; \
    KEYUPD(accA##I.x, n0 + tx*4 + 0) KEYUPD(accA##I.y, n0 + tx*4 + 1) \
    KEYUPD(accA##I.z, n0 + tx*4 + 2) KEYUPD(accA##I.w, n0 + tx*4 + 3) \
    KEYUPD(accB##I.x, n0 + 64 + tx*4 + 0) KEYUPD(accB##I.y, n0 + 64 + tx*4 + 1) \
    KEYUPD(accB##I.z, n0 + 64 + tx*4 + 2) KEYUPD(accB##I.w, n0 + 64 + tx*4 + 3) \
    _Pragma("unroll") \
    for (int s = 1; s < 16; s <<= 1) { unsigned long long o = shfl_xor_u64_w16(best, s); if (o < best) best = o; } \
    if (tx == 0) atomicMin(&keybuf[m], best); }

__global__ __launch_bounds__(256, 2) void vq_gemm_argmin(const float* __restrict__ A, const float* __restrict__ cb,
                               const float* __restrict__ c2, const float* __restrict__ r2,
                               unsigned long long* __restrict__ keybuf) {
    __shared__ float As[32][260];
    __shared__ float Bs[32][132];
    int m0 = blockIdx.y * 256;
    int n0 = blockIdx.x * 128;
    int tid = threadIdx.x;
    int tx = tid & 15;
    int ty = tid >> 4;
    int kq = tid & 7;         // staging k-quad 0..7
    int rq = tid >> 3;        // staging row-quad 0..31

    DECL(0) DECL(1) DECL(2) DECL(3) DECL(4) DECL(5) DECL(6) DECL(7)
    DECL(8) DECL(9) DECL(10) DECL(11) DECL(12) DECL(13) DECL(14) DECL(15)

    const float* Ab0 = A  + (size_t)(m0 + rq * 4) * 512 + kq * 4;
    const float* Ab1 = A  + (size_t)(m0 + 128 + rq * 4) * 512 + kq * 4;
    const float* Bb  = cb + (size_t)(n0 + rq * 4) * 512 + kq * 4;

    for (int k0 = 0; k0 < 512; k0 += 32) {
        float4 pa0 = *(const float4*)(Ab0 + 0 * 512 + k0);
        float4 pa1 = *(const float4*)(Ab0 + 1 * 512 + k0);
        float4 pa2 = *(const float4*)(Ab0 + 2 * 512 + k0);
        float4 pa3 = *(const float4*)(Ab0 + 3 * 512 + k0);
        float4 qa0 = *(const float4*)(Ab1 + 0 * 512 + k0);
        float4 qa1 = *(const float4*)(Ab1 + 1 * 512 + k0);
        float4 qa2 = *(const float4*)(Ab1 + 2 * 512 + k0);
        float4 qa3 = *(const float4*)(Ab1 + 3 * 512 + k0);
        float4 pb0 = *(const float4*)(Bb  + 0 * 512 + k0);
        float4 pb1 = *(const float4*)(Bb  + 1 * 512 + k0);
        float4 pb2 = *(const float4*)(Bb  + 2 * 512 + k0);
        float4 pb3 = *(const float4*)(Bb  + 3 * 512 + k0);
        __syncthreads();                       // previous compute done before overwrite
        XP(As, kq * 4, rq * 4,       pa0, pa1, pa2, pa3)
        XP(As, kq * 4, 128 + rq * 4, qa0, qa1, qa2, qa3)
        XP(Bs, kq * 4, rq * 4,       pb0, pb1, pb2, pb3)
        __syncthreads();
        #pragma unroll
        for (int kk = 0; kk < 32; ++kk) {
            float4 a0 = *(const float4*)&As[kk][ty * 4];
            float4 a1 = *(const float4*)&As[kk][64 + ty * 4];
            float4 a2 = *(const float4*)&As[kk][128 + ty * 4];
            float4 a3 = *(const float4*)&As[kk][192 + ty * 4];
            float4 b0 = *(const float4*)&Bs[kk][tx * 4];
            float4 b1 = *(const float4*)&Bs[kk][64 + tx * 4];
            RF(0,  a0.x) RF(1,  a0.y) RF(2,  a0.z) RF(3,  a0.w)
            RF(4,  a1.x) RF(5,  a1.y) RF(6,  a1.z) RF(7,  a1.w)
            RF(8,  a2.x) RF(9,  a2.y) RF(10, a2.z) RF(11, a2.w)
            RF(12, a3.x) RF(13, a3.y) RF(14, a3.z) RF(15, a3.w)
        }
    }
    EPI(0) EPI(1) EPI(2) EPI(3) EPI(4) EPI(5) EPI(6) EPI(7)
    EPI(8) EPI(9) EPI(10) EPI(11) EPI(12) EPI(13) EPI(14) EPI(15)
}

// ---------------- VQ apply: residual update, commit partial, indices ----------------
__global__ void vq_apply(const float* __restrict__ cb, const unsigned long long* __restrict__ keybuf,
                         float* __restrict__ R, float* __restrict__ r2,
                         float* __restrict__ idx_f, int* __restrict__ idx_i,
                         float* __restrict__ slots, int q, int write_r) {
    __shared__ float red[256];
    int m = blockIdx.x;
    int tid = threadIdx.x;
    unsigned idx = (unsigned)(keybuf[m] & 0xFFFFFFFFull);
    const float* c = cb + (size_t)idx * 512;
    float* r = R + (size_t)m * 512;
    float s = 0.f;
    for (int c0 = tid; c0 < 512; c0 += 256) {
        float nr = r[c0] - c[c0];
        if (write_r) r[c0] = nr;
        s += nr * nr;
    }
    red[tid] = s; __syncthreads();
    for (int st = 128; st > 0; st >>= 1) { if (tid < st) red[tid] += red[tid + st]; __syncthreads(); }
    if (tid == 0) {
        if (write_r) r2[m] = red[0];
        atomicAdd(&slots[512 + q * 512 + (m & 511)], red[0]);
        idx_f[(size_t)m * 2 + q] = (float)idx;
        idx_i[m * 2 + q] = (int)idx;
    }
}

// ---------------- quantized output (channel-major) via LDS transpose ----------------
__global__ void quant_out_kernel(const float* __restrict__ cb0, const float* __restrict__ cb1,
                                 const int* __restrict__ idxi, float* __restrict__ out4) {
    __shared__ float buf[64][129];
    __shared__ int i0s[64], i1s[64];
    int b = blockIdx.x;
    int t0 = blockIdx.y * 64;
    int c0 = blockIdx.z * 128;
    int tid = threadIdx.x;
    if (tid < 64) {
        int t = t0 + tid;
        int i0 = 0, i1 = 0;
        if (t < T4L) { i0 = idxi[(b * T4L + t) * 2]; i1 = idxi[(b * T4L + t) * 2 + 1]; }
        i0s[tid] = i0; i1s[tid] = i1;
    }
    __syncthreads();
    int cl = tid & 127, th = tid >> 7;
    for (int t = th; t < 64; t += 2) {
        if (t0 + t < T4L)
            buf[t][cl] = cb0[(size_t)i0s[t] * 512 + c0 + cl] + cb1[(size_t)i1s[t] * 512 + c0 + cl];
    }
    __syncthreads();
    int lane = tid & 63, ch = tid >> 6;
    for (int cc = ch; cc < 128; cc += 4) {
        int t = t0 + lane;
        if (t < T4L) out4[((size_t)b * 512 + c0 + cc) * T4L + t] = buf[lane][cc];
    }
}

// ---------------- final 1x1 conv + recon loss ----------------
__global__ void dec_final_kernel(const float* __restrict__ d2buf, const float* __restrict__ W,
                                 const float* __restrict__ bb, const float* __restrict__ img,
                                 float* __restrict__ out, float* __restrict__ slots) {
    __shared__ float red[256];
    int tok = blockIdx.x * 256 + threadIdx.x;   // 1632 blocks * 256 = 417792 exact
    float acc = bb[0];
    const float* row = d2buf + (size_t)tok * 64;
    #pragma unroll
    for (int i = 0; i < 16; ++i) {
        float4 v = *(const float4*)(row + i * 4);
        float4 w = *(const float4*)(W + i * 4);
        acc += v.x * w.x + v.y * w.y + v.z * w.z + v.w * w.w;
    }
    out[tok] = acc;
    float d = img[tok] - acc;
    red[threadIdx.x] = d * d; __syncthreads();
    for (int s = 128; s > 0; s >>= 1) { if (threadIdx.x < s) red[threadIdx.x] += red[threadIdx.x + s]; __syncthreads(); }
    if (threadIdx.x == 0) atomicAdd(&slots[blockIdx.x & 511], red[0]);
}

// ---------------- finalize losses ----------------
__global__ void finalize_kernel(const float* __restrict__ slots, float* __restrict__ out_scalars) {
    __shared__ float red[256];
    int tid = threadIdx.x;
    for (int which = 0; which < 3; ++which) {
        float s = slots[which * 512 + tid] + slots[which * 512 + tid + 256];
        red[tid] = s; __syncthreads();
        for (int st = 128; st > 0; st >>= 1) { if (tid < st) red[tid] += red[tid + st]; __syncthreads(); }
        if (tid == 0) {
            float denom = (which == 0) ? (float)MOUT : (float)((size_t)MTOK * 512);
            out_scalars[which] = red[0] / denom;
        }
        __syncthreads();
    }
}

// ---------------- launch ----------------
extern "C" void kernel_launch(void* const* d_in, const int* in_sizes, int n_in,
                              void* d_out, int out_size, void* d_ws, size_t ws_size,
                              hipStream_t stream) {
    const float* img  = (const float*)d_in[0];
    const float* We1  = (const float*)d_in[1];
    const float* be1  = (const float*)d_in[2];
    const float* We2  = (const float*)d_in[3];
    const float* be2  = (const float*)d_in[4];
    const float* We3  = (const float*)d_in[5];
    const float* be3  = (const float*)d_in[6];
    const float* cbs  = (const float*)d_in[7];   // [2,1024,512]
    const float* Wtd1 = (const float*)d_in[8];
    const float* bd1  = (const float*)d_in[9];
    const float* Wtd2 = (const float*)d_in[10];
    const float* bd2  = (const float*)d_in[11];
    const float* Wd3  = (const float*)d_in[12];
    const float* bd3  = (const float*)d_in[13];

    float* w = (float*)d_ws;
    float* xr   = w + OFF_XR;        // tokens / residual; later reused as d2buf
    float* h1   = w + OFF_H1;        // later reused as d1
    float* h2   = w + OFF_H2;
    float* Be2  = w + OFF_BE2;
    float* Bd1  = w + OFF_BD1;
    float* Bd2  = w + OFF_BD2;
    float* bx1  = w + OFF_BX1;
    float* bx2  = w + OFF_BX2;
    float* c2   = w + OFF_C2;
    float* r2   = w + OFF_R2;
    float* slots= w + OFF_SLOT;
    int*   idxi = (int*)(w + OFF_IDXI);
    unsigned long long* keys = (unsigned long long*)(w + OFF_KEYS);

    float* outp = (float*)d_out;
    float* out0   = outp + DO_OUT;
    float* oscal  = outp + DO_RECON;    // recon, commit0, commit1 contiguous
    float* idxf   = outp + DO_IDX;
    float* qout   = outp + DO_QUANT;

    // init: argmin keys to +inf, loss slots to zero
    hipMemsetAsync(keys, 0xFF, 2 * (size_t)MTOK * sizeof(unsigned long long), stream);
    hipMemsetAsync(slots, 0, 1536 * sizeof(float), stream);

    prep_kernel<<<64, 256, 0, stream>>>(We2, Wtd1, Wtd2, bd1, bd2, Be2, Bd1, Bd2, bx1, bx2);
    rownorm_kernel<<<(2048 * 64) / 256, 256, 0, stream>>>(cbs, c2, 2048);

    // encoder
    enc1_kernel<<<(NB * T2L * HIDC) / 256, 256, 0, stream>>>(img, We1, be1, h1);
    gemm_nt<<<dim3(MTOK / 128, 1), 256, 0, stream>>>(h1, Be2, be2, h2, MTOK, 64, 128, 1, 0, 1);
    gemm_nt<<<dim3(MTOK / 128, 8), 256, 0, stream>>>(h2, We3, be3, xr, MTOK, 512, 64, 0, 0, 0);
    rownorm_kernel<<<((size_t)MTOK * 64) / 256, 256, 0, stream>>>(xr, r2, MTOK);

    // residual VQ, q = 0
    vq_gemm_argmin<<<dim3(8, MTOK / 256), 256, 0, stream>>>(xr, cbs, c2, r2, keys);
    vq_apply<<<MTOK, 256, 0, stream>>>(cbs, keys, xr, r2, idxf, idxi, slots, 0, 1);
    // q = 1
    vq_gemm_argmin<<<dim3(8, MTOK / 256), 256, 0, stream>>>(xr, cbs + (size_t)NTOK * CBD, c2 + NTOK, r2, keys + MTOK);
    vq_apply<<<MTOK, 256, 0, stream>>>(cbs + (size_t)NTOK * CBD, keys + MTOK, xr, r2, idxf, idxi, slots, 1, 0);

    // quantized output [B,512,408]
    quant_out_kernel<<<dim3(NB, 7, 4), 256, 0, stream>>>(cbs, cbs + (size_t)NTOK * CBD, idxi, qout);

    // decoder: convT1 (A = quantized channel-major), d1 reuses h1 region
    gemm_nt<<<dim3(MTOK / 128, 2), 256, 0, stream>>>(qout, Bd1, bx1, h1, MTOK, 128, 512, 2, 1, 1);
    // convT2: d2buf reuses xr region
    gemm_nt<<<dim3(M2TOK / 128, 2), 256, 0, stream>>>(h1, Bd2, bx2, xr, M2TOK, 128, 64, 0, 2, 1);
    // final 1x1 + recon loss
    dec_final_kernel<<<MOUT / 256, 256, 0, stream>>>(xr, Wd3, bd3, img, out0, slots);

    finalize_kernel<<<1, 256, 0, stream>>>(slots, oscal);
}

// Round 6
// 1877.509 us; speedup vs baseline: 1.9867x; 1.9867x over previous
//
#include <hip/hip_runtime.h>

// ---------------- problem constants ----------------
#define NB    256
#define TLEN  1632
#define HIDC  64
#define CBD   512
#define NTOK  1024
#define T2L   816          // after enc conv1
#define T4L   408          // after enc conv2 (token count per batch)
#define MTOK  (NB*T4L)     // 104448 tokens
#define M2TOK (NB*T2L)     // 208896
#define MOUT  (NB*TLEN)    // 417792
#define TAU   0.05f        // rescue margin: >> 3-term bf16 split error bound (~1e-3)

// d_out flat offsets (floats)
#define DO_OUT    ((size_t)0)
#define DO_RECON  ((size_t)417792)
#define DO_COMMIT ((size_t)417793)
#define DO_IDX    ((size_t)417795)
#define DO_QUANT  ((size_t)626691)

// ---------------- workspace layout (float indices) ----------------
static constexpr size_t N_XR   = (size_t)MTOK * CBD;        // xr/residual; later d2buf
static constexpr size_t OFF_XR = 0;
static constexpr size_t OFF_H1 = OFF_XR + N_XR;             // h1, later d1
static constexpr size_t N_H1   = (size_t)NB * T2L * HIDC;
static constexpr size_t OFF_H2 = OFF_H1 + N_H1;             // h2
static constexpr size_t N_H2   = (size_t)NB * T4L * HIDC;
static constexpr size_t OFF_BE2 = OFF_H2 + N_H2;            // 64*128
static constexpr size_t OFF_BD1 = OFF_BE2 + 8192;           // 128*512
static constexpr size_t OFF_BD2 = OFF_BD1 + 65536;          // 128*64
static constexpr size_t OFF_BX1 = OFF_BD2 + 8192;
static constexpr size_t OFF_BX2 = OFF_BX1 + 128;
static constexpr size_t OFF_C2  = OFF_BX2 + 128;            // 2048 codebook norms
static constexpr size_t OFF_R2  = OFF_C2 + 2048;            // token norms
static constexpr size_t OFF_SLOT= OFF_R2 + MTOK;            // 1536 loss slots
static constexpr size_t OFF_IDXI= OFF_SLOT + 1536;          // MTOK*2 ints
static constexpr size_t OFF_KEYS= OFF_IDXI + (size_t)MTOK*2;// 2*MTOK u64
static constexpr size_t OFF_PAIRS=OFF_KEYS + (size_t)MTOK*4;// MTOK*16 u64 (top2 per block)
static constexpr size_t OFF_FC  = OFF_PAIRS + (size_t)MTOK*32; // 2 ints
static constexpr size_t OFF_FLAG= OFF_FC + 2;               // 2*MTOK ints

// ---------------- types / helpers ----------------
typedef __attribute__((ext_vector_type(8))) short short8;   // 8 bf16
typedef __attribute__((ext_vector_type(4))) float f32x4;

__device__ inline unsigned long long shfl_xor_u64_w16(unsigned long long v, int m) {
    unsigned lo = (unsigned)v, hi = (unsigned)(v >> 32);
    lo = __shfl_xor(lo, m, 16);
    hi = __shfl_xor(hi, m, 16);
    return (((unsigned long long)hi) << 32) | lo;
}
__device__ inline unsigned long long packkey(float d, int n) {
    unsigned u = __float_as_uint(d);
    u = (u & 0x80000000u) ? ~u : (u | 0x80000000u);   // monotonic map
    return (((unsigned long long)u) << 32) | (unsigned)n;
}
__device__ inline float unpackd(unsigned long long k) {
    unsigned u = (unsigned)(k >> 32);
    u = (u & 0x80000000u) ? (u & 0x7fffffffu) : ~u;
    return __uint_as_float(u);
}
// merge two sorted pairs -> global top2 (keeps (k1<=k2) invariant)
__device__ inline void merge2(unsigned long long& k1, unsigned long long& k2,
                              unsigned long long o1, unsigned long long o2) {
    unsigned long long n1 = (k1 < o1) ? k1 : o1;
    unsigned long long hi = (k1 < o1) ? o1 : k1;
    unsigned long long cand = (k1 <= o1) ? k2 : o2;
    unsigned long long n2 = (hi < cand) ? hi : cand;
    k1 = n1; k2 = n2;
}
// split 16 fp32 -> bf16 hi (truncate) + bf16 lo, store 2x16B to hp and lp
__device__ inline void storeSplit(short* hp, short* lp,
                                  float4 a0, float4 a1, float4 a2, float4 a3) {
    float v[16] = {a0.x,a0.y,a0.z,a0.w, a1.x,a1.y,a1.z,a1.w,
                   a2.x,a2.y,a2.z,a2.w, a3.x,a3.y,a3.z,a3.w};
    short8 h0, h1, l0, l1;
    #pragma unroll
    for (int i = 0; i < 8; ++i) {
        unsigned xb = __float_as_uint(v[i]);
        h0[i] = (short)(xb >> 16);
        float lo = v[i] - __uint_as_float(xb & 0xFFFF0000u);
        l0[i] = (short)(__float_as_uint(lo) >> 16);
    }
    #pragma unroll
    for (int i = 0; i < 8; ++i) {
        unsigned xb = __float_as_uint(v[8 + i]);
        h1[i] = (short)(xb >> 16);
        float lo = v[8 + i] - __uint_as_float(xb & 0xFFFF0000u);
        l1[i] = (short)(__float_as_uint(lo) >> 16);
    }
    *(short8*)hp = h0; *((short8*)hp + 1) = h1;
    *(short8*)lp = l0; *((short8*)lp + 1) = l1;
}

// ---------------- weight prep ----------------
__global__ void prep_kernel(const float* __restrict__ We2, const float* __restrict__ Wtd1,
                            const float* __restrict__ Wtd2, const float* __restrict__ bd1,
                            const float* __restrict__ bd2,
                            float* __restrict__ Be2, float* __restrict__ Bd1,
                            float* __restrict__ Bd2, float* __restrict__ bx1, float* __restrict__ bx2) {
    int i = blockIdx.x * blockDim.x + threadIdx.x;
    int stride = gridDim.x * blockDim.x;
    for (int x = i; x < 64 * 128; x += stride) {
        int c = x >> 7, k = x & 127;
        Be2[x] = We2[c * 128 + ((k & 63) << 1) + (k >> 6)];
    }
    for (int x = i; x < 128 * 512; x += stride) {
        int n = x >> 9, k = x & 511;
        Bd1[x] = Wtd1[k * 128 + n];
    }
    for (int x = i; x < 128 * 64; x += stride) {
        int n = x >> 6, k = x & 63;
        Bd2[x] = Wtd2[k * 128 + n];
    }
    for (int x = i; x < 128; x += stride) { bx1[x] = bd1[x >> 1]; bx2[x] = bd2[x >> 1]; }
}

// ---------------- row sum-of-squares (512-wide rows) ----------------
__global__ void rownorm_kernel(const float* __restrict__ X, float* __restrict__ out, int rows) {
    int w = (blockIdx.x * blockDim.x + threadIdx.x) >> 6;
    int lane = threadIdx.x & 63;
    if (w >= rows) return;
    const float* r = X + (size_t)w * 512;
    float4 a = *(const float4*)(r + lane * 8);
    float4 b = *(const float4*)(r + lane * 8 + 4);
    float s = a.x*a.x + a.y*a.y + a.z*a.z + a.w*a.w + b.x*b.x + b.y*b.y + b.z*b.z + b.w*b.w;
    #pragma unroll
    for (int o = 32; o > 0; o >>= 1) s += __shfl_down(s, o, 64);
    if (lane == 0) out[w] = s;
}

// ---------------- encoder conv1 ----------------
__global__ void enc1_kernel(const float* __restrict__ img, const float* __restrict__ W,
                            const float* __restrict__ bias, float* __restrict__ h1) {
    int idx = blockIdx.x * 256 + threadIdx.x;
    int c = idx & 63;
    int t = (idx >> 6) % T2L;
    int b = idx / (64 * T2L);
    float v = W[c * 2] * img[(size_t)b * TLEN + 2 * t] +
              W[c * 2 + 1] * img[(size_t)b * TLEN + 2 * t + 1] + bias[c];
    h1[idx] = fmaxf(v, 0.f);
}

// ---------------- generic NT SGEMM (small convs) ----------------
__global__ __launch_bounds__(256) void gemm_nt(const float* __restrict__ A, const float* __restrict__ Bw,
                        const float* __restrict__ bias, float* __restrict__ C,
                        int M, int N, int K, int amode, int cmode, int relu) {
    __shared__ float As[32][132];
    __shared__ float Bs[32][68];
    int m0 = blockIdx.x * 128;
    int n0 = blockIdx.y * 64;
    int tid = threadIdx.x;
    int tx = tid & 15;
    int ty = tid >> 4;
    float acc[8][4];
    #pragma unroll
    for (int i = 0; i < 8; ++i)
        #pragma unroll
        for (int j = 0; j < 4; ++j) acc[i][j] = 0.f;

    for (int k0 = 0; k0 < K; k0 += 32) {
        if (amode != 2) {
            #pragma unroll
            for (int i = 0; i < 4; ++i) {
                int idx = tid + i * 256;
                int row = idx >> 3;
                int kq = idx & 7;
                int m = m0 + row;
                size_t base;
                if (amode == 0) base = (size_t)m * K;
                else            base = (size_t)(((m / T4L) * T2L + 2 * (m % T4L)) * 64);
                float4 v = *(const float4*)(A + base + k0 + kq * 4);
                int kk = kq * 4;
                As[kk + 0][row] = v.x; As[kk + 1][row] = v.y;
                As[kk + 2][row] = v.z; As[kk + 3][row] = v.w;
            }
        } else {
            int ml = tid & 127;
            int kl = tid >> 7;
            int m = m0 + ml;
            int b = m / T4L, t = m % T4L;
            size_t rowbase = ((size_t)b * 512) * T4L + t;
            for (int kk = kl; kk < 32; kk += 2)
                As[kk][ml] = A[rowbase + (size_t)(k0 + kk) * T4L];
        }
        #pragma unroll
        for (int i = 0; i < 2; ++i) {
            int idx = tid + i * 256;
            int row = idx >> 3;
            int kq = idx & 7;
            float4 v = *(const float4*)(Bw + (size_t)(n0 + row) * K + k0 + kq * 4);
            int kk = kq * 4;
            Bs[kk + 0][row] = v.x; Bs[kk + 1][row] = v.y;
            Bs[kk + 2][row] = v.z; Bs[kk + 3][row] = v.w;
        }
        __syncthreads();
        #pragma unroll
        for (int kk = 0; kk < 32; ++kk) {
            float a[8], bf[4];
            float4 a0 = *(const float4*)&As[kk][ty * 8];
            float4 a1 = *(const float4*)&As[kk][ty * 8 + 4];
            a[0]=a0.x; a[1]=a0.y; a[2]=a0.z; a[3]=a0.w;
            a[4]=a1.x; a[5]=a1.y; a[6]=a1.z; a[7]=a1.w;
            float4 b0 = *(const float4*)&Bs[kk][tx * 4];
            bf[0]=b0.x; bf[1]=b0.y; bf[2]=b0.z; bf[3]=b0.w;
            #pragma unroll
            for (int i = 0; i < 8; ++i)
                #pragma unroll
                for (int j = 0; j < 4; ++j) acc[i][j] += a[i] * bf[j];
        }
        __syncthreads();
    }
    #pragma unroll
    for (int i = 0; i < 8; ++i) {
        int m = m0 + ty * 8 + i;
        if (cmode == 0) {
            float4 v;
            v.x = acc[i][0] + bias[n0 + tx * 4 + 0];
            v.y = acc[i][1] + bias[n0 + tx * 4 + 1];
            v.z = acc[i][2] + bias[n0 + tx * 4 + 2];
            v.w = acc[i][3] + bias[n0 + tx * 4 + 3];
            if (relu) { v.x=fmaxf(v.x,0.f); v.y=fmaxf(v.y,0.f); v.z=fmaxf(v.z,0.f); v.w=fmaxf(v.w,0.f); }
            *(float4*)(C + (size_t)m * N + n0 + tx * 4) = v;
        } else {
            int Tin = (cmode == 1) ? T4L : T2L;
            int Texp = 2 * Tin;
            int bb = m / Tin, t = m % Tin;
            #pragma unroll
            for (int j = 0; j < 4; ++j) {
                int n = n0 + tx * 4 + j;
                float v = acc[i][j] + bias[n];
                if (relu) v = fmaxf(v, 0.f);
                size_t off = (size_t)((bb * Texp + 2 * t + (n & 1)) * 64 + (n >> 1));
                C[off] = v;
            }
        }
    }
}

// ---------------- VQ distance via split-bf16 MFMA + per-block top-2 ----------------
// Tile 128(M) x 128(N), BK=32. 4 waves = 2x2 (wm,wn), each computes 64x64 via 4x4
// mfma_f32_16x16x32_bf16 tiles, 3 MFMAs per tile-step (hi*hi + hi*lo + lo*hi).
// A-frag: A[m=lane&15][k=quad*8+j]; C/D: col=lane&15, row=quad*4+reg (m89/m91-verified).
__global__ __launch_bounds__(256) void vq_mfma_top2(const float* __restrict__ A, const float* __restrict__ cb,
                              const float* __restrict__ c2, const float* __restrict__ r2,
                              unsigned long long* __restrict__ pairs) {
    __shared__ short Ah[128][40], Al[128][40], Bh[128][40], Bl[128][40];
    __shared__ float r2s[128], c2s[128];
    __shared__ unsigned long long top2s[4][64][2];
    int tid = threadIdx.x;
    int n0 = blockIdx.x * 128, m0 = blockIdx.y * 128;
    int lane = tid & 63, wid = tid >> 6;
    int wm = wid >> 1, wn = wid & 1;
    int lm = lane & 15, quad = lane >> 4;
    if (tid < 128) r2s[tid] = r2[m0 + tid];
    else           c2s[tid - 128] = c2[n0 + tid - 128];

    f32x4 acc[4][4];
    #pragma unroll
    for (int i = 0; i < 4; ++i)
        #pragma unroll
        for (int j = 0; j < 4; ++j) acc[i][j] = (f32x4){0.f, 0.f, 0.f, 0.f};

    int srow = tid >> 1, shalf = tid & 1;
    const float* Asrc = A  + (size_t)(m0 + srow) * 512 + shalf * 16;
    const float* Bsrc = cb + (size_t)(n0 + srow) * 512 + shalf * 16;

    for (int k0 = 0; k0 < 512; k0 += 32) {
        float4 a0 = *(const float4*)(Asrc + k0);
        float4 a1 = *(const float4*)(Asrc + k0 + 4);
        float4 a2 = *(const float4*)(Asrc + k0 + 8);
        float4 a3 = *(const float4*)(Asrc + k0 + 12);
        float4 b0 = *(const float4*)(Bsrc + k0);
        float4 b1 = *(const float4*)(Bsrc + k0 + 4);
        float4 b2 = *(const float4*)(Bsrc + k0 + 8);
        float4 b3 = *(const float4*)(Bsrc + k0 + 12);
        __syncthreads();                          // previous compute done before overwrite
        storeSplit(&Ah[srow][shalf * 16], &Al[srow][shalf * 16], a0, a1, a2, a3);
        storeSplit(&Bh[srow][shalf * 16], &Bl[srow][shalf * 16], b0, b1, b2, b3);
        __syncthreads();
        short8 bh[4], bl[4];
        #pragma unroll
        for (int nt = 0; nt < 4; ++nt) {
            bh[nt] = *(const short8*)&Bh[wn * 64 + nt * 16 + lm][quad * 8];
            bl[nt] = *(const short8*)&Bl[wn * 64 + nt * 16 + lm][quad * 8];
        }
        #pragma unroll
        for (int mt = 0; mt < 4; ++mt) {
            short8 ah = *(const short8*)&Ah[wm * 64 + mt * 16 + lm][quad * 8];
            short8 al = *(const short8*)&Al[wm * 64 + mt * 16 + lm][quad * 8];
            #pragma unroll
            for (int nt = 0; nt < 4; ++nt) {
                acc[mt][nt] = __builtin_amdgcn_mfma_f32_16x16x32_bf16(al, bh[nt], acc[mt][nt], 0, 0, 0);
                acc[mt][nt] = __builtin_amdgcn_mfma_f32_16x16x32_bf16(ah, bl[nt], acc[mt][nt], 0, 0, 0);
                acc[mt][nt] = __builtin_amdgcn_mfma_f32_16x16x32_bf16(ah, bh[nt], acc[mt][nt], 0, 0, 0);
            }
        }
    }
    // epilogue: per-row local top2 over this block's 128 codes
    #pragma unroll
    for (int mt = 0; mt < 4; ++mt) {
        #pragma unroll
        for (int r = 0; r < 4; ++r) {
            int rloc = mt * 16 + quad * 4 + r;
            float rr = r2s[wm * 64 + rloc];
            unsigned long long k1 = ~0ull, k2 = ~0ull;
            #pragma unroll
            for (int nt = 0; nt < 4; ++nt) {
                int nl = wn * 64 + nt * 16 + lm;
                float d = (rr - 2.0f * acc[mt][nt][r]) + c2s[nl];
                unsigned long long k = packkey(d, n0 + nl);
                if (k < k1) { k2 = k1; k1 = k; } else if (k < k2) { k2 = k; }
            }
            #pragma unroll
            for (int s = 1; s < 16; s <<= 1) {
                unsigned long long o1 = shfl_xor_u64_w16(k1, s);
                unsigned long long o2 = shfl_xor_u64_w16(k2, s);
                merge2(k1, k2, o1, o2);
            }
            if (lm == 0) { top2s[wid][rloc][0] = k1; top2s[wid][rloc][1] = k2; }
        }
    }
    __syncthreads();
    if (tid < 128) {
        int wmv = tid >> 6, row = tid & 63;
        unsigned long long a1 = top2s[wmv * 2][row][0], a2 = top2s[wmv * 2][row][1];
        merge2(a1, a2, top2s[wmv * 2 + 1][row][0], top2s[wmv * 2 + 1][row][1]);
        size_t base = ((size_t)(m0 + wmv * 64 + row)) * 16 + blockIdx.x * 2;
        pairs[base] = a1; pairs[base + 1] = a2;
    }
}

// ---------------- reduce: global top2 per token, flag near-ties ----------------
__global__ void vq_reduce(const unsigned long long* __restrict__ pairs,
                          unsigned long long* __restrict__ keybuf,
                          int* __restrict__ fc, int* __restrict__ flaglist) {
    int m = blockIdx.x * 256 + threadIdx.x;
    const unsigned long long* p = pairs + (size_t)m * 16;
    unsigned long long k1 = ~0ull, k2 = ~0ull;
    #pragma unroll
    for (int i = 0; i < 16; ++i) {
        unsigned long long k = p[i];
        if (k < k1) { k2 = k1; k1 = k; } else if (k < k2) { k2 = k; }
    }
    keybuf[m] = k1;
    if (unpackd(k2) - unpackd(k1) < TAU) {
        int pos = atomicAdd(fc, 1);
        flaglist[pos] = m;
    }
}

// ---------------- rescue: exact fp32 argmin for flagged tokens ----------------
__global__ void vq_rescue(const float* __restrict__ xr, const float* __restrict__ cb,
                          const float* __restrict__ c2, const float* __restrict__ r2,
                          const int* __restrict__ fc, const int* __restrict__ flaglist,
                          unsigned long long* __restrict__ keybuf) {
    __shared__ unsigned long long red[4];
    int cnt = *fc;
    int lane = threadIdx.x & 63, wid = threadIdx.x >> 6;
    for (int f = blockIdx.x; f < cnt; f += gridDim.x) {
        int m = flaglist[f];
        float4 rv0 = *(const float4*)(xr + (size_t)m * 512 + lane * 8);
        float4 rv1 = *(const float4*)(xr + (size_t)m * 512 + lane * 8 + 4);
        float rr = r2[m];
        unsigned long long best = ~0ull;
        for (int c = wid * 256; c < wid * 256 + 256; ++c) {
            const float* cp = cb + (size_t)c * 512 + lane * 8;
            float4 c0 = *(const float4*)cp;
            float4 c1 = *(const float4*)(cp + 4);
            float p = rv0.x*c0.x + rv0.y*c0.y + rv0.z*c0.z + rv0.w*c0.w
                    + rv1.x*c1.x + rv1.y*c1.y + rv1.z*c1.z + rv1.w*c1.w;
            #pragma unroll
            for (int s = 1; s < 64; s <<= 1) p += __shfl_xor(p, s, 64);
            unsigned long long k = packkey((rr - 2.0f * p) + c2[c], c);
            if (k < best) best = k;
        }
        if (lane == 0) red[wid] = best;
        __syncthreads();
        if (threadIdx.x == 0) {
            unsigned long long b = red[0];
            if (red[1] < b) b = red[1];
            if (red[2] < b) b = red[2];
            if (red[3] < b) b = red[3];
            keybuf[m] = b;
        }
        __syncthreads();
    }
}

// ---------------- VQ apply: residual update, commit partial, indices ----------------
__global__ void vq_apply(const float* __restrict__ cb, const unsigned long long* __restrict__ keybuf,
                         float* __restrict__ R, float* __restrict__ r2,
                         float* __restrict__ idx_f, int* __restrict__ idx_i,
                         float* __restrict__ slots, int q, int write_r) {
    __shared__ float red[256];
    int m = blockIdx.x;
    int tid = threadIdx.x;
    unsigned idx = (unsigned)(keybuf[m] & 0xFFFFFFFFull);
    const float* c = cb + (size_t)idx * 512;
    float* r = R + (size_t)m * 512;
    float s = 0.f;
    for (int c0 = tid; c0 < 512; c0 += 256) {
        float nr = r[c0] - c[c0];
        if (write_r) r[c0] = nr;
        s += nr * nr;
    }
    red[tid] = s; __syncthreads();
    for (int st = 128; st > 0; st >>= 1) { if (tid < st) red[tid] += red[tid + st]; __syncthreads(); }
    if (tid == 0) {
        if (write_r) r2[m] = red[0];
        atomicAdd(&slots[512 + q * 512 + (m & 511)], red[0]);
        idx_f[(size_t)m * 2 + q] = (float)idx;
        idx_i[m * 2 + q] = (int)idx;
    }
}

// ---------------- quantized output (channel-major) via LDS transpose ----------------
__global__ void quant_out_kernel(const float* __restrict__ cb0, const float* __restrict__ cb1,
                                 const int* __restrict__ idxi, float* __restrict__ out4) {
    __shared__ float buf[64][129];
    __shared__ int i0s[64], i1s[64];
    int b = blockIdx.x;
    int t0 = blockIdx.y * 64;
    int c0 = blockIdx.z * 128;
    int tid = threadIdx.x;
    if (tid < 64) {
        int t = t0 + tid;
        int i0 = 0, i1 = 0;
        if (t < T4L) { i0 = idxi[(b * T4L + t) * 2]; i1 = idxi[(b * T4L + t) * 2 + 1]; }
        i0s[tid] = i0; i1s[tid] = i1;
    }
    __syncthreads();
    int cl = tid & 127, th = tid >> 7;
    for (int t = th; t < 64; t += 2) {
        if (t0 + t < T4L)
            buf[t][cl] = cb0[(size_t)i0s[t] * 512 + c0 + cl] + cb1[(size_t)i1s[t] * 512 + c0 + cl];
    }
    __syncthreads();
    int lane = tid & 63, ch = tid >> 6;
    for (int cc = ch; cc < 128; cc += 4) {
        int t = t0 + lane;
        if (t < T4L) out4[((size_t)b * 512 + c0 + cc) * T4L + t] = buf[lane][cc];
    }
}

// ---------------- final 1x1 conv + recon loss ----------------
__global__ void dec_final_kernel(const float* __restrict__ d2buf, const float* __restrict__ W,
                                 const float* __restrict__ bb, const float* __restrict__ img,
                                 float* __restrict__ out, float* __restrict__ slots) {
    __shared__ float red[256];
    int tok = blockIdx.x * 256 + threadIdx.x;
    float acc = bb[0];
    const float* row = d2buf + (size_t)tok * 64;
    #pragma unroll
    for (int i = 0; i < 16; ++i) {
        float4 v = *(const float4*)(row + i * 4);
        float4 w = *(const float4*)(W + i * 4);
        acc += v.x * w.x + v.y * w.y + v.z * w.z + v.w * w.w;
    }
    out[tok] = acc;
    float d = img[tok] - acc;
    red[threadIdx.x] = d * d; __syncthreads();
    for (int s = 128; s > 0; s >>= 1) { if (threadIdx.x < s) red[threadIdx.x] += red[threadIdx.x + s]; __syncthreads(); }
    if (threadIdx.x == 0) atomicAdd(&slots[blockIdx.x & 511], red[0]);
}

// ---------------- finalize losses ----------------
__global__ void finalize_kernel(const float* __restrict__ slots, float* __restrict__ out_scalars) {
    __shared__ float red[256];
    int tid = threadIdx.x;
    for (int which = 0; which < 3; ++which) {
        float s = slots[which * 512 + tid] + slots[which * 512 + tid + 256];
        red[tid] = s; __syncthreads();
        for (int st = 128; st > 0; st >>= 1) { if (tid < st) red[tid] += red[tid + st]; __syncthreads(); }
        if (tid == 0) {
            float denom = (which == 0) ? (float)MOUT : (float)((size_t)MTOK * 512);
            out_scalars[which] = red[0] / denom;
        }
        __syncthreads();
    }
}

// ---------------- launch ----------------
extern "C" void kernel_launch(void* const* d_in, const int* in_sizes, int n_in,
                              void* d_out, int out_size, void* d_ws, size_t ws_size,
                              hipStream_t stream) {
    const float* img  = (const float*)d_in[0];
    const float* We1  = (const float*)d_in[1];
    const float* be1  = (const float*)d_in[2];
    const float* We2  = (const float*)d_in[3];
    const float* be2  = (const float*)d_in[4];
    const float* We3  = (const float*)d_in[5];
    const float* be3  = (const float*)d_in[6];
    const float* cbs  = (const float*)d_in[7];   // [2,1024,512]
    const float* Wtd1 = (const float*)d_in[8];
    const float* bd1  = (const float*)d_in[9];
    const float* Wtd2 = (const float*)d_in[10];
    const float* bd2  = (const float*)d_in[11];
    const float* Wd3  = (const float*)d_in[12];
    const float* bd3  = (const float*)d_in[13];

    float* w = (float*)d_ws;
    float* xr   = w + OFF_XR;
    float* h1   = w + OFF_H1;
    float* h2   = w + OFF_H2;
    float* Be2  = w + OFF_BE2;
    float* Bd1  = w + OFF_BD1;
    float* Bd2  = w + OFF_BD2;
    float* bx1  = w + OFF_BX1;
    float* bx2  = w + OFF_BX2;
    float* c2   = w + OFF_C2;
    float* r2   = w + OFF_R2;
    float* slots= w + OFF_SLOT;
    int*   idxi = (int*)(w + OFF_IDXI);
    unsigned long long* keys  = (unsigned long long*)(w + OFF_KEYS);
    unsigned long long* pairs = (unsigned long long*)(w + OFF_PAIRS);
    int*   fc   = (int*)(w + OFF_FC);
    int*   flag = (int*)(w + OFF_FLAG);

    float* outp = (float*)d_out;
    float* out0   = outp + DO_OUT;
    float* oscal  = outp + DO_RECON;
    float* idxf   = outp + DO_IDX;
    float* qout   = outp + DO_QUANT;

    hipMemsetAsync(slots, 0, 1536 * sizeof(float), stream);
    hipMemsetAsync(fc, 0, 2 * sizeof(int), stream);

    prep_kernel<<<64, 256, 0, stream>>>(We2, Wtd1, Wtd2, bd1, bd2, Be2, Bd1, Bd2, bx1, bx2);
    rownorm_kernel<<<(2048 * 64) / 256, 256, 0, stream>>>(cbs, c2, 2048);

    // encoder
    enc1_kernel<<<(NB * T2L * HIDC) / 256, 256, 0, stream>>>(img, We1, be1, h1);
    gemm_nt<<<dim3(MTOK / 128, 1), 256, 0, stream>>>(h1, Be2, be2, h2, MTOK, 64, 128, 1, 0, 1);
    gemm_nt<<<dim3(MTOK / 128, 8), 256, 0, stream>>>(h2, We3, be3, xr, MTOK, 512, 64, 0, 0, 0);
    rownorm_kernel<<<((size_t)MTOK * 64) / 256, 256, 0, stream>>>(xr, r2, MTOK);

    const float* cb1p = cbs + (size_t)NTOK * CBD;

    // residual VQ, q = 0
    vq_mfma_top2<<<dim3(8, MTOK / 128), 256, 0, stream>>>(xr, cbs, c2, r2, pairs);
    vq_reduce<<<MTOK / 256, 256, 0, stream>>>(pairs, keys, fc + 0, flag);
    vq_rescue<<<1024, 256, 0, stream>>>(xr, cbs, c2, r2, fc + 0, flag, keys);
    vq_apply<<<MTOK, 256, 0, stream>>>(cbs, keys, xr, r2, idxf, idxi, slots, 0, 1);
    // q = 1
    vq_mfma_top2<<<dim3(8, MTOK / 128), 256, 0, stream>>>(xr, cb1p, c2 + NTOK, r2, pairs);
    vq_reduce<<<MTOK / 256, 256, 0, stream>>>(pairs, keys + MTOK, fc + 1, flag + MTOK);
    vq_rescue<<<1024, 256, 0, stream>>>(xr, cb1p, c2 + NTOK, r2, fc + 1, flag + MTOK, keys + MTOK);
    vq_apply<<<MTOK, 256, 0, stream>>>(cb1p, keys + MTOK, xr, r2, idxf, idxi, slots, 1, 0);

    // quantized output [B,512,408]
    quant_out_kernel<<<dim3(NB, 7, 4), 256, 0, stream>>>(cbs, cb1p, idxi, qout);

    // decoder
    gemm_nt<<<dim3(MTOK / 128, 2), 256, 0, stream>>>(qout, Bd1, bx1, h1, MTOK, 128, 512, 2, 1, 1);
    gemm_nt<<<dim3(M2TOK / 128, 2), 256, 0, stream>>>(h1, Bd2, bx2, xr, M2TOK, 128, 64, 0, 2, 1);
    dec_final_kernel<<<MOUT / 256, 256, 0, stream>>>(xr, Wd3, bd3, img, out0, slots);

    finalize_kernel<<<1, 256, 0, stream>>>(slots, oscal);
}